// Round 6
// baseline (520.751 us; speedup 1.0000x reference)
//
#include <hip/hip_runtime.h>
#include <math.h>

// ---------------------------------------------------------------------------
// NFM forward, fused split-fp16 MFMA kernel. R6: staged split planes (convert
// once) + double-buffered B fragments (L2 latency hidden).
//   - 32-row blocks, 256 thr (4 waves), 4096 blocks, 3 blocks/CU (50.8KB LDS),
//     __launch_bounds__(256,3).
//   - Staging threads load x f32, convert ONCE to {hi,lo}-packed u32 plane +
//     sq f16 plane in LDS; lin dot fused. Frag reads: ds_read_b128 + v_perm.
//   - FM/l1/l2 K-loops: manual even/odd B-frag double buffer, unroll 1 ->
//     next iter's global B loads in flight across current MFMAs, no spill.
//   - Zero barriers inside K-loops; 7 barriers/block total.
// Stages: FM tmp=0.5*((x@V)^2+(x^2)@(V^2)) [xv split x3 + sq x1];
//   l1/l2/l3 tower split-f16; out = sigmoid(lin + deep).
// MFMA v_mfma_f32_16x16x32_f16, verified layouts:
//   A[m=lane&15][k=(lane>>4)*8+j]; D: col=lane&15, row=(lane>>4)*4+reg.
// ---------------------------------------------------------------------------

typedef _Float16 f16;
typedef _Float16 f16x4 __attribute__((ext_vector_type(4)));
typedef _Float16 f16x8 __attribute__((ext_vector_type(8)));
typedef float f32x4 __attribute__((ext_vector_type(4)));
typedef unsigned int u32;
typedef u32 u32x4 __attribute__((ext_vector_type(4)));

#define NROWS   131072
#define ROWS    32
#define FDIM    256
#define KDIM    256
#define D1      128
#define D2      85

// workspace byte offsets (weights only, ~600KB, L2-resident)
#define OFF_VT_H   0x0UL       // [256][256] f16
#define OFF_VT_L   0x20000UL
#define OFF_V2T    0x40000UL
#define OFF_W1T_H  0x60000UL   // [128][256] f16
#define OFF_W1T_L  0x70000UL
#define OFF_W2T_H  0x80000UL   // [128][128] f16 (N padded 85->128)
#define OFF_W2T_L  0x88000UL
#define OFF_W3T_H  0x90000UL   // [64][96] f16 (K padded 85->96)
#define OFF_W3T_L  0x93000UL

static __device__ __forceinline__ f32x4 mfma16(f16x8 a, f16x8 b, f32x4 c) {
  return __builtin_amdgcn_mfma_f32_16x16x32_f16(a, b, c, 0, 0, 0);
}

static __device__ __forceinline__ u32 pack2(float v) {
  f16 hi = (f16)v;
  f16 lo = (f16)(v - (float)hi);
  union { f16 f[2]; u32 u; } t;
  t.f[0] = hi;
  t.f[1] = lo;
  return t.u;
}

static __device__ __forceinline__ void unpack8(u32x4 a, u32x4 b, f16x8* H,
                                               f16x8* L) {
  union { u32 u; f16 f[2]; } t;
  u32 w[8] = {a.x, a.y, a.z, a.w, b.x, b.y, b.z, b.w};
#pragma unroll
  for (int j = 0; j < 8; ++j) {
    t.u = w[j];
    (*H)[j] = t.f[0];
    (*L)[j] = t.f[1];
  }
}

// ---------------------------------------------------------------------------
__global__ __launch_bounds__(256) void prep_kernel(
    const float* __restrict__ V, const float* __restrict__ w1,
    const float* __restrict__ w2, const float* __restrict__ w3,
    f16* VT_h, f16* VT_l, f16* V2T,
    f16* W1T_h, f16* W1T_l, f16* W2T_h, f16* W2T_l, f16* W3T_h, f16* W3T_l) {
  int idx0 = blockIdx.x * 256 + threadIdx.x;
  int stride = gridDim.x * 256;
  for (int idx = idx0; idx < KDIM * FDIM; idx += stride) {
    int k = idx >> 8, i = idx & 255;          // VT[k][i] = V[i][k]
    float v = V[i * KDIM + k];
    f16 h = (f16)v;
    VT_h[idx] = h;
    VT_l[idx] = (f16)(v - (float)h);
    V2T[idx] = (f16)(v * v);
  }
  for (int idx = idx0; idx < D1 * KDIM; idx += stride) {
    int n = idx >> 8, k = idx & 255;          // W1T[n][k] = w1[k][n]
    float w = w1[k * D1 + n];
    f16 h = (f16)w;
    W1T_h[idx] = h;
    W1T_l[idx] = (f16)(w - (float)h);
  }
  for (int idx = idx0; idx < 128 * 128; idx += stride) {
    int n = idx >> 7, k = idx & 127;          // W2T[n][k], n>=85 -> 0
    float w = (n < D2) ? w2[k * D2 + n] : 0.f;
    f16 h = (f16)w;
    W2T_h[idx] = h;
    W2T_l[idx] = (f16)(w - (float)h);
  }
  for (int idx = idx0; idx < 64 * 96; idx += stride) {
    int n = idx / 96, k = idx - n * 96;       // W3T[n][k], k>=85 -> 0
    float w = (k < D2) ? w3[k * 64 + n] : 0.f;
    f16 h = (f16)w;
    W3T_h[idx] = h;
    W3T_l[idx] = (f16)(w - (float)h);
  }
}

// ---------------------------------------------------------------------------
struct FmB { f16x8 h[4], l[4]; };
struct TwB { f16x8 h[2], l[2]; };

static __device__ __forceinline__ void fm_loadB(const f16* __restrict__ VT_h,
                                                const f16* __restrict__ VT_l,
                                                int base, FmB* B) {
#pragma unroll
  for (int ni = 0; ni < 4; ++ni) {
    int boff = base + ni * (16 * FDIM);
    B->h[ni] = *(const f16x8*)(VT_h + boff);
    B->l[ni] = *(const f16x8*)(VT_l + boff);
  }
}

static __device__ __forceinline__ void fm_step(const u32* xS, const f16* sqS,
                                               int k0, int ln, int q,
                                               const FmB& B, const f16x8* B2,
                                               f32x4 accV[2][4],
                                               f32x4 acc2[2][4]) {
  f16x8 A2[2];
#pragma unroll
  for (int mi = 0; mi < 2; ++mi) {
    const u32* tp = xS + (mi * 16 + ln) * 260 + k0 + q * 8;
    u32x4 p0 = *(const u32x4*)tp;
    u32x4 p1 = *(const u32x4*)(tp + 4);
    f16x8 Ah, Al;
    unpack8(p0, p1, &Ah, &Al);
    A2[mi] = *(const f16x8*)(sqS + (mi * 16 + ln) * 264 + k0 + q * 8);
#pragma unroll
    for (int ni = 0; ni < 4; ++ni) {
      accV[mi][ni] = mfma16(Al, B.h[ni], accV[mi][ni]);
      accV[mi][ni] = mfma16(Ah, B.l[ni], accV[mi][ni]);
      accV[mi][ni] = mfma16(Ah, B.h[ni], accV[mi][ni]);
    }
  }
#pragma unroll
  for (int mi = 0; mi < 2; ++mi)
#pragma unroll
    for (int ni = 0; ni < 4; ++ni)
      acc2[mi][ni] = mfma16(A2[mi], B2[ni], acc2[mi][ni]);
}

static __device__ __forceinline__ void tw_loadB(const f16* __restrict__ Wh,
                                                const f16* __restrict__ Wl,
                                                int base, int nstride, TwB* B) {
#pragma unroll
  for (int nj = 0; nj < 2; ++nj) {
    int boff = base + nj * nstride;
    B->h[nj] = *(const f16x8*)(Wh + boff);
    B->l[nj] = *(const f16x8*)(Wl + boff);
  }
}

static __device__ __forceinline__ void tw_step(const u32* aS, int astride,
                                               int k0, int ln, int q,
                                               const TwB& B, f32x4 acc[2][2]) {
#pragma unroll
  for (int mi = 0; mi < 2; ++mi) {
    const u32* tp = aS + (mi * 16 + ln) * astride + k0 + q * 8;
    u32x4 p0 = *(const u32x4*)tp;
    u32x4 p1 = *(const u32x4*)(tp + 4);
    f16x8 Ah, Al;
    unpack8(p0, p1, &Ah, &Al);
#pragma unroll
    for (int nj = 0; nj < 2; ++nj) {
      acc[mi][nj] = mfma16(Al, B.h[nj], acc[mi][nj]);
      acc[mi][nj] = mfma16(Ah, B.l[nj], acc[mi][nj]);
      acc[mi][nj] = mfma16(Ah, B.h[nj], acc[mi][nj]);
    }
  }
}

// ---------------------------------------------------------------------------
__global__ __launch_bounds__(256, 3) void fused_kernel(
    const float* __restrict__ x, const float* __restrict__ w_wide,
    const float* __restrict__ b_wide,
    const f16* __restrict__ VT_h, const f16* __restrict__ VT_l,
    const f16* __restrict__ V2T,
    const f16* __restrict__ W1T_h, const f16* __restrict__ W1T_l,
    const float* __restrict__ b1,
    const f16* __restrict__ W2T_h, const f16* __restrict__ W2T_l,
    const float* __restrict__ b2,
    const f16* __restrict__ W3T_h, const f16* __restrict__ W3T_l,
    const float* __restrict__ b3,
    const float* __restrict__ w_out, const float* __restrict__ b_out,
    float* __restrict__ out) {
  // AR1 (u32[32*260], off 0):    x hi|lo -> tmp hi|lo -> h2 hi|lo
  // AR2 (u32[32*132], off 8320): sq plane (f16 [32][264]) -> h1 hi|lo
  __shared__ __align__(16) u32 arena[32 * 260 + 32 * 132];
  __shared__ float linS[ROWS];
  __shared__ float pfS[ROWS * 4];

  const int tid = threadIdx.x;
  const int lane = tid & 63, wv = tid >> 6;   // wv 0..3
  const int q = lane >> 4, ln = lane & 15;
  const int row0 = blockIdx.x * ROWS;

  // ---- staging: load x, convert ONCE to split planes, fused lin dot -------
  {
    const int lr = tid >> 3, lj = tid & 7;
    const float* xg = x + (size_t)(row0 + lr) * FDIM + lj * 4;
    u32* xrow = arena + lr * 260;
    f16* sqrow = (f16*)(arena + 8320) + lr * 264;
    float lp = 0.f;
#pragma unroll
    for (int t = 0; t < 8; ++t) {
      const int c = lj * 4 + t * 32;
      float4 v = *(const float4*)(xg + t * 32);
      float4 w = *(const float4*)(w_wide + c);
      lp += v.x * w.x + v.y * w.y + v.z * w.z + v.w * w.w;
      float f[4] = {v.x, v.y, v.z, v.w};
      u32x4 p;
      f16x4 s;
#pragma unroll
      for (int j = 0; j < 4; ++j) {
        p[j] = pack2(f[j]);
        s[j] = (f16)(f[j] * f[j]);
      }
      *(u32x4*)(xrow + c) = p;
      *(f16x4*)(sqrow + c) = s;
    }
    lp += __shfl_xor(lp, 1);
    lp += __shfl_xor(lp, 2);
    lp += __shfl_xor(lp, 4);
    if (lj == 0) linS[lr] = lp + b_wide[0];
  }
  __syncthreads();  // B1: planes ready

  // ---- FM: 2 m-tiles x 4 n-tiles per wave, K=256, B double-buffered -------
  f32x4 accV[2][4], acc2[2][4];
#pragma unroll
  for (int i = 0; i < 2; ++i)
#pragma unroll
    for (int j = 0; j < 4; ++j) {
      accV[i][j] = (f32x4){0.f, 0.f, 0.f, 0.f};
      acc2[i][j] = (f32x4){0.f, 0.f, 0.f, 0.f};
    }
  {
    const u32* xS = arena;
    const f16* sqS = (const f16*)(arena + 8320);
    const int bbase = (wv * 64 + ln) * FDIM + q * 8;
    FmB Ba, Bb;
    f16x8 B2c[4];
    fm_loadB(VT_h, VT_l, bbase, &Ba);
#pragma unroll 1
    for (int ks2 = 0; ks2 < 4; ++ks2) {
      const int k0 = ks2 * 64;
      // even: consume Ba@k0, prefetch Bb@k0+32
#pragma unroll
      for (int ni = 0; ni < 4; ++ni)
        B2c[ni] = *(const f16x8*)(V2T + bbase + ni * (16 * FDIM) + k0);
      fm_loadB(VT_h, VT_l, bbase + k0 + 32, &Bb);
      fm_step(xS, sqS, k0, ln, q, Ba, B2c, accV, acc2);
      // odd: consume Bb@k0+32, prefetch Ba@k0+64
#pragma unroll
      for (int ni = 0; ni < 4; ++ni)
        B2c[ni] = *(const f16x8*)(V2T + bbase + ni * (16 * FDIM) + k0 + 32);
      if (ks2 < 3) fm_loadB(VT_h, VT_l, bbase + k0 + 64, &Ba);
      fm_step(xS, sqS, k0 + 32, ln, q, Bb, B2c, accV, acc2);
    }
  }
  __syncthreads();  // B2: x plane reads done; AR1 reusable

  // ---- FM epilogue: tmp {hi,lo} u32, stride 260, AR1 ----------------------
  {
    u32* tmpS = arena;
#pragma unroll
    for (int mi = 0; mi < 2; ++mi)
#pragma unroll
      for (int r = 0; r < 4; ++r) {
        int m = mi * 16 + q * 4 + r;
        u32* rowp = tmpS + m * 260;
#pragma unroll
        for (int ni = 0; ni < 4; ++ni) {
          int n = wv * 64 + ni * 16 + ln;
          float xv = accV[mi][ni][r];
          rowp[n] = pack2(0.5f * (xv * xv + acc2[mi][ni][r]));
        }
      }
  }
  __syncthreads();  // B3: tmp ready

  // ---- l1: h1 = relu(tmp@w1+b1), N=128, K=256, B double-buffered ----------
  f32x4 acc1[2][2];
#pragma unroll
  for (int i = 0; i < 2; ++i) {
    acc1[i][0] = (f32x4){0.f, 0.f, 0.f, 0.f};
    acc1[i][1] = (f32x4){0.f, 0.f, 0.f, 0.f};
  }
  {
    const u32* tmpS = arena;
    const int base1 = (wv * 32 + ln) * KDIM + q * 8;
    TwB Ba, Bb;
    tw_loadB(W1T_h, W1T_l, base1, 16 * KDIM, &Ba);
#pragma unroll 1
    for (int ks2 = 0; ks2 < 4; ++ks2) {
      const int k0 = ks2 * 64;
      tw_loadB(W1T_h, W1T_l, base1 + k0 + 32, 16 * KDIM, &Bb);
      tw_step(tmpS, 260, k0, ln, q, Ba, acc1);
      if (ks2 < 3) tw_loadB(W1T_h, W1T_l, base1 + k0 + 64, 16 * KDIM, &Ba);
      tw_step(tmpS, 260, k0 + 32, ln, q, Bb, acc1);
    }
  }
  // l1 epilogue -> AR2 (sq dead): no barrier needed before writes
  {
    u32* h1S = arena + 8320;
#pragma unroll
    for (int mi = 0; mi < 2; ++mi)
#pragma unroll
      for (int r = 0; r < 4; ++r) {
        int m = mi * 16 + q * 4 + r;
#pragma unroll
        for (int nj = 0; nj < 2; ++nj) {
          int n = wv * 32 + nj * 16 + ln;
          float z = acc1[mi][nj][r] + b1[n];
          h1S[m * 132 + n] = pack2(z > 0.f ? z : 0.f);
        }
      }
  }
  __syncthreads();  // B4: h1 ready

  // ---- l2: h2 = relu(h1@w2+b2), N=128(pad), K=128, B double-buffered ------
  f32x4 accL2[2][2];
#pragma unroll
  for (int i = 0; i < 2; ++i) {
    accL2[i][0] = (f32x4){0.f, 0.f, 0.f, 0.f};
    accL2[i][1] = (f32x4){0.f, 0.f, 0.f, 0.f};
  }
  {
    const u32* h1S = arena + 8320;
    const int base2 = (wv * 32 + ln) * 128 + q * 8;
    TwB Ba, Bb;
    tw_loadB(W2T_h, W2T_l, base2, 16 * 128, &Ba);
#pragma unroll 1
    for (int ks2 = 0; ks2 < 2; ++ks2) {
      const int k0 = ks2 * 64;
      tw_loadB(W2T_h, W2T_l, base2 + k0 + 32, 16 * 128, &Bb);
      tw_step(h1S, 132, k0, ln, q, Ba, accL2);
      if (ks2 < 1) tw_loadB(W2T_h, W2T_l, base2 + k0 + 64, 16 * 128, &Ba);
      tw_step(h1S, 132, k0 + 32, ln, q, Bb, accL2);
    }
  }
  // l2 epilogue -> h2 in AR1 (tmp dead): no barrier before writes
  {
    u32* h2S = arena;
#pragma unroll
    for (int mi = 0; mi < 2; ++mi)
#pragma unroll
      for (int r = 0; r < 4; ++r) {
        int m = mi * 16 + q * 4 + r;
#pragma unroll
        for (int nj = 0; nj < 2; ++nj) {
          int n = wv * 32 + nj * 16 + ln;
          if (n < 96) {
            float z = accL2[mi][nj][r] + ((n < D2) ? b2[n] : 0.f);
            h2S[m * 100 + n] = pack2(z > 0.f ? z : 0.f);
          }
        }
      }
  }
  __syncthreads();  // B5: h2 ready

  // ---- l3: K=96, N=64; 2mi x 1 n-tile per wave + final dot ----------------
  f32x4 acc3[2];
  acc3[0] = (f32x4){0.f, 0.f, 0.f, 0.f};
  acc3[1] = (f32x4){0.f, 0.f, 0.f, 0.f};
  {
    const u32* h2S = arena;
    const int n3 = wv * 16 + ln;
#pragma unroll
    for (int ks = 0; ks < 3; ++ks) {
      const int k0 = ks * 32;
      int boff = n3 * 96 + k0 + q * 8;
      f16x8 Bh = *(const f16x8*)(W3T_h + boff);
      f16x8 Bl = *(const f16x8*)(W3T_l + boff);
#pragma unroll
      for (int mi = 0; mi < 2; ++mi) {
        const u32* hp = h2S + (mi * 16 + ln) * 100 + k0 + q * 8;
        u32x4 p0 = *(const u32x4*)hp;
        u32x4 p1 = *(const u32x4*)(hp + 4);
        f16x8 Ah, Al;
        unpack8(p0, p1, &Ah, &Al);
        acc3[mi] = mfma16(Al, Bh, acc3[mi]);
        acc3[mi] = mfma16(Ah, Bl, acc3[mi]);
        acc3[mi] = mfma16(Ah, Bh, acc3[mi]);
      }
    }
  }
  {
    const int n3 = wv * 16 + ln;
    float b3v = b3[n3], wov = w_out[n3];
#pragma unroll
    for (int mi = 0; mi < 2; ++mi)
#pragma unroll
      for (int r = 0; r < 4; ++r) {
        float z = acc3[mi][r] + b3v;
        float part = (z > 0.f ? z : 0.f) * wov;
        part += __shfl_xor(part, 1);
        part += __shfl_xor(part, 2);
        part += __shfl_xor(part, 4);
        part += __shfl_xor(part, 8);
        if (ln == 0) pfS[(mi * 16 + q * 4 + r) * 4 + wv] = part;
      }
  }
  __syncthreads();  // B6: partials ready

  if (tid < ROWS) {
    float zf = linS[tid] + pfS[tid * 4] + pfS[tid * 4 + 1] + pfS[tid * 4 + 2] +
               pfS[tid * 4 + 3] + b_out[0];
    out[row0 + tid] = 1.f / (1.f + expf(-zf));
  }
}

// ---------------------------------------------------------------------------
extern "C" void kernel_launch(void* const* d_in, const int* in_sizes, int n_in,
                              void* d_out, int out_size, void* d_ws, size_t ws_size,
                              hipStream_t stream) {
  const float* x = (const float*)d_in[0];
  const float* w_wide = (const float*)d_in[1];
  const float* b_wide = (const float*)d_in[2];
  const float* V = (const float*)d_in[3];
  const float* w1 = (const float*)d_in[4];
  const float* b1 = (const float*)d_in[5];
  const float* w2 = (const float*)d_in[6];
  const float* b2 = (const float*)d_in[7];
  const float* w3 = (const float*)d_in[8];
  const float* b3 = (const float*)d_in[9];
  const float* w_out = (const float*)d_in[10];
  const float* b_out = (const float*)d_in[11];
  float* out = (float*)d_out;
  char* ws = (char*)d_ws;

  f16* VT_h = (f16*)(ws + OFF_VT_H);
  f16* VT_l = (f16*)(ws + OFF_VT_L);
  f16* V2T = (f16*)(ws + OFF_V2T);
  f16* W1T_h = (f16*)(ws + OFF_W1T_H);
  f16* W1T_l = (f16*)(ws + OFF_W1T_L);
  f16* W2T_h = (f16*)(ws + OFF_W2T_H);
  f16* W2T_l = (f16*)(ws + OFF_W2T_L);
  f16* W3T_h = (f16*)(ws + OFF_W3T_H);
  f16* W3T_l = (f16*)(ws + OFF_W3T_L);

  prep_kernel<<<64, 256, 0, stream>>>(V, w1, w2, w3, VT_h, VT_l, V2T, W1T_h,
                                      W1T_l, W2T_h, W2T_l, W3T_h, W3T_l);

  fused_kernel<<<NROWS / ROWS, 256, 0, stream>>>(
      x, w_wide, b_wide, VT_h, VT_l, V2T, W1T_h, W1T_l, b1, W2T_h, W2T_l, b2,
      W3T_h, W3T_l, b3, w_out, b_out, out);
}